// Round 2
// baseline (852.049 us; speedup 1.0000x reference)
//
#include <hip/hip_runtime.h>
#include <hip/hip_bf16.h>
#include <math.h>

#define NJ 17
#define DD 128
#define TT 512
#define HH 16
#define CC 256
#define NEG_INF -9e15f

typedef __attribute__((ext_vector_type(8))) short short8;
typedef __attribute__((ext_vector_type(4))) float floatx4;
typedef _Float16 h8 __attribute__((ext_vector_type(8)));
typedef _Float16 h2 __attribute__((ext_vector_type(2)));

// ws BYTE offsets
#define WB_CONV 0            // bf16[65536]  conv_w*bnscale, fragment order (16 nt x 8 ks x 64 lane x 8)
#define WB_QKV  131072       // bf16[49152]  [Wq|Wk|Wv] cols, fragment order (24 nt x 4 ks x 64 lane x 8)
#define WB_MOFF 229376       // f32[16*17*17] additive mask offsets
#define WB_BIAS 247872       // f32[256]     fused BN bias
#define PREP_ITEMS (65536 + 49152 + 4624 + 256)

__global__ __launch_bounds__(256) void prep_kernel(
        const float* __restrict__ adj,
        const float* __restrict__ wq,
        const float* __restrict__ wk,
        const float* __restrict__ wv,
        const float* __restrict__ adj2,
        const float* __restrict__ conv_w,
        const float* __restrict__ gamma,
        const float* __restrict__ beta,
        const float* __restrict__ mean,
        const float* __restrict__ var,
        char* __restrict__ ws) {
    int g = blockIdx.x * 256 + threadIdx.x;
    if (g < 65536) {
        // conv fragments: idx = ((nt*8+ks)*64+lane)*8+j ; o = nt*16+(lane&15), c = ks*32+(lane>>4)*8+j
        int j = g & 7, lane = (g >> 3) & 63, kn = g >> 9;
        int ks = kn & 7, nt = kn >> 3;
        int o = nt * 16 + (lane & 15);
        int c = ks * 32 + ((lane >> 4) & 3) * 8 + j;
        float sg = gamma[o] * rsqrtf(var[o] + 1e-5f);
        ((__hip_bfloat16*)(ws + WB_CONV))[g] = __float2bfloat16(conv_w[o * CC + c] * sg);
        return;
    }
    g -= 65536;
    if (g < 49152) {
        // qkv fragments: idx = ((nt*4+ks)*64+lane)*8+j ; n = nt*16+(lane&15), k = ks*32+(lane>>4)*8+j
        int j = g & 7, lane = (g >> 3) & 63, kn = g >> 9;
        int ks = kn & 3, nt = kn >> 2;            // nt 0..23 over 384 cols: [q|k|v]
        int n = nt * 16 + (lane & 15);
        int k = ks * 32 + ((lane >> 4) & 3) * 8 + j;
        int mat = n >> 7;                          // 0=q 1=k 2=v
        int wcol = n & 127;
        int h = wcol >> 3, e = wcol & 7;
        const float* src = (mat == 0) ? wq : ((mat == 1) ? wk : wv);
        float v = src[(h * DD + k) * 8 + e];       // (H,D,hd) layout
        if (mat == 0) v *= 0.35355339059327373f;   // 1/sqrt(8) folded into Wq
        ((__hip_bfloat16*)(ws + WB_QKV))[g] = __float2bfloat16(v);
        return;
    }
    g -= 49152;
    if (g < HH * NJ * NJ) {
        int h = g / (NJ * NJ);
        int r = g - h * NJ * NJ;
        int n = r / NJ, m = r - n * NJ;
        float a1 = adj[n * NJ + m] + adj2[(h * NJ + n) * NJ + m];
        float a2 = adj[m * NJ + n] + adj2[(h * NJ + m) * NJ + n];
        ((float*)(ws + WB_MOFF))[g] = (0.5f * (a1 + a2) > 0.f) ? 0.f : NEG_INF;
        return;
    }
    g -= HH * NJ * NJ;
    if (g < CC) {
        float sg = gamma[g] * rsqrtf(var[g] + 1e-5f);
        ((float*)(ws + WB_BIAS))[g] = beta[g] - mean[g] * sg;
    }
}

// LDS layout:
//   cat: 34 rows x 264 bf16 (stride 528 B). cols 0..127 = xp, cols 128..255 = q (f16 bits,
//        phase 1/2) then attention output (bf16, phase 2/3).
//   kv : 2 x 34 x 128 f16 (k, v)
// MFMA M-tiles read "rows" 32..47; rows 34..47 are garbage (they alias kv) — harmless,
// since MFMA output rows are independent and rows >=34 are never stored.
#define CAT_STRIDE 264
#define LDS_CAT_BYTES (34 * CAT_STRIDE * 2)
#define LDS_TOTAL (LDS_CAT_BYTES + 2 * 34 * 128 * 2)

__global__ __launch_bounds__(512, 6) void gab_main(
        const float* __restrict__ x,
        const char* __restrict__ ws,
        float* __restrict__ out) {
    // t-swizzle: XCD x gets a contiguous t-range so adjacent write runs merge in one L2
    const int tp = blockIdx.x;                       // 0..255 (token pairs)
    const int t0 = 2 * ((tp & 7) * 32 + (tp >> 3));
    const int b = blockIdx.y;
    const int tid = threadIdx.x;
    const int lane = tid & 63;
    const int wave = tid >> 6;                       // 0..7
    const int l15 = lane & 15;
    const int lq = lane >> 4;

    __shared__ __align__(16) char smem[LDS_TOTAL];
    __hip_bfloat16 (*cat)[CAT_STRIDE] = (__hip_bfloat16 (*)[CAT_STRIDE])smem;
    _Float16 (*kv)[34][128] = (_Float16 (*)[34][128])(smem + LDS_CAT_BYTES);

    // ---- Phase 0: stage xp -> cat[row][d] (row = lt*17+n). No zero-fill needed. ----
    const float* xb = x + (size_t)b * DD * TT * NJ + (size_t)t0 * NJ;
    for (int i = tid; i < DD * 17; i += 512) {
        int d = i / 17;
        int j = 2 * (i - d * 17);                   // 17 float2 cover j=0..33
        float2 f = *(const float2*)(xb + (size_t)d * (TT * NJ) + j);
        cat[j][d] = __float2bfloat16(f.x);
        cat[j + 1][d] = __float2bfloat16(f.y);
    }
    __syncthreads();

    // ---- Phase 1: QKV GEMM via MFMA. wave w owns Ntiles w*3..w*3+2 of 24 (cols: q|k|v) ----
    {
        const short8* bbase = (const short8*)(ws + WB_QKV);
        const int nt0 = wave * 3;
        for (int i = 0; i < 3; ++i) {
            const int nt = nt0 + i;
            floatx4 acc0 = {0.f, 0.f, 0.f, 0.f}, acc1 = acc0, acc2 = acc0;
            const short8* bp = bbase + (nt * 4) * 64 + lane;
#pragma unroll
            for (int ks = 0; ks < 4; ++ks) {
                short8 bf = bp[ks * 64];
                const int k0 = ks * 32 + lq * 8;
                short8 a0 = *(const short8*)&cat[l15][k0];
                short8 a1 = *(const short8*)&cat[16 + l15][k0];
                short8 a2 = *(const short8*)&cat[32 + l15][k0];   // rows 34..47: garbage, discarded
                acc0 = __builtin_amdgcn_mfma_f32_16x16x32_bf16(a0, bf, acc0, 0, 0, 0);
                acc1 = __builtin_amdgcn_mfma_f32_16x16x32_bf16(a1, bf, acc1, 0, 0, 0);
                acc2 = __builtin_amdgcn_mfma_f32_16x16x32_bf16(a2, bf, acc2, 0, 0, 0);
            }
            const int col = nt * 16 + l15;
            const int mat = col >> 7;                // wave-uniform (16-col tiles never straddle 128)
            const int mc = col & 127;
            const int rbase = lq * 4;
            if (mat == 0) {
                // q lives as f16 bits in cat's attn half; consumed (and overwritten) in phase 2
                _Float16* qd = (_Float16*)smem + 128 + mc;
#pragma unroll
                for (int r = 0; r < 4; ++r) {
                    qd[(rbase + r) * CAT_STRIDE] = (_Float16)acc0[r];
                    qd[(16 + rbase + r) * CAT_STRIDE] = (_Float16)acc1[r];
                    int row2 = 32 + rbase + r;
                    if (row2 < 34) qd[row2 * CAT_STRIDE] = (_Float16)acc2[r];
                }
            } else {
                _Float16* kd = &kv[mat - 1][0][mc];
#pragma unroll
                for (int r = 0; r < 4; ++r) {
                    kd[(rbase + r) * 128] = (_Float16)acc0[r];
                    kd[(16 + rbase + r) * 128] = (_Float16)acc1[r];
                    int row2 = 32 + rbase + r;
                    if (row2 < 34) kd[row2 * 128] = (_Float16)acc2[r];
                }
            }
        }
    }
    __syncthreads();

    // ---- Phase 2: attention per (t,h,n). q read from cat (f16), output overwrites it (bf16). ----
    {
        const float* moff = (const float*)(ws + WB_MOFF);
        for (int it = tid; it < 2 * HH * NJ; it += 512) {
            const int t = it / (HH * NJ);
            const int r2 = it - t * (HH * NJ);
            const int h = r2 / NJ;
            const int n = r2 - h * NJ;
            const int row = t * NJ + n;
            const float* mo = moff + (h * NJ + n) * NJ;
            const h8 qv = *(const h8*)((const _Float16*)smem + row * CAT_STRIDE + 128 + h * 8);
            const h2* q2 = (const h2*)&qv;
            float s[NJ];
            float mx = -3.4e38f;
#pragma unroll
            for (int m = 0; m < NJ; ++m) {
                const h8 kvec = *(const h8*)&kv[0][t * NJ + m][h * 8];
                float a = mo[m];
#if __has_builtin(__builtin_amdgcn_fdot2)
                const h2* k2 = (const h2*)&kvec;
                a = __builtin_amdgcn_fdot2(q2[0], k2[0], a, false);
                a = __builtin_amdgcn_fdot2(q2[1], k2[1], a, false);
                a = __builtin_amdgcn_fdot2(q2[2], k2[2], a, false);
                a = __builtin_amdgcn_fdot2(q2[3], k2[3], a, false);
#else
#pragma unroll
                for (int e = 0; e < 8; ++e) a += (float)qv[e] * (float)kvec[e];
#endif
                s[m] = a;
                mx = fmaxf(mx, a);
            }
            float sum = 0.f;
#pragma unroll
            for (int m = 0; m < NJ; ++m) {
                float p = __expf(s[m] - mx);
                s[m] = p;
                sum += p;
            }
            const float inv = 1.0f / sum;
            float ov[8];
#pragma unroll
            for (int e = 0; e < 8; ++e) ov[e] = 0.f;
#pragma unroll
            for (int m = 0; m < NJ; ++m) {
                const h8 vvec = *(const h8*)&kv[1][t * NJ + m][h * 8];
                const float p = s[m];
#pragma unroll
                for (int e = 0; e < 8; ++e) ov[e] += p * (float)vvec[e];
            }
            __hip_bfloat16 tmp[8];
#pragma unroll
            for (int e = 0; e < 8; ++e) tmp[e] = __float2bfloat16(ov[e] * inv);
            *(short8*)((__hip_bfloat16*)smem + row * CAT_STRIDE + 128 + h * 8) = *(short8*)tmp;
        }
    }
    __syncthreads();

    // ---- Phase 3: conv1x1 GEMM via MFMA + BN bias + ReLU. wave w owns Ntiles w*2..w*2+1 ----
    {
        const short8* cbase = (const short8*)(ws + WB_CONV);
        const float* biasp = (const float*)(ws + WB_BIAS);
        const int nt0 = wave * 2;
        for (int i = 0; i < 2; ++i) {
            const int nt = nt0 + i;
            floatx4 acc0 = {0.f, 0.f, 0.f, 0.f}, acc1 = acc0, acc2 = acc0;
            const short8* bp = cbase + (nt * 8) * 64 + lane;
#pragma unroll
            for (int ks = 0; ks < 8; ++ks) {
                short8 bf = bp[ks * 64];
                const int k0 = ks * 32 + lq * 8;
                short8 a0 = *(const short8*)&cat[l15][k0];
                short8 a1 = *(const short8*)&cat[16 + l15][k0];
                short8 a2 = *(const short8*)&cat[32 + l15][k0];   // rows 34..47: garbage, discarded
                acc0 = __builtin_amdgcn_mfma_f32_16x16x32_bf16(a0, bf, acc0, 0, 0, 0);
                acc1 = __builtin_amdgcn_mfma_f32_16x16x32_bf16(a1, bf, acc1, 0, 0, 0);
                acc2 = __builtin_amdgcn_mfma_f32_16x16x32_bf16(a2, bf, acc2, 0, 0, 0);
            }
            const int o = nt * 16 + l15;
            const float bias = biasp[o];
            const size_t ob = ((size_t)b * CC + o) * (TT * NJ) + (size_t)t0 * NJ;
            const int rbase = lq * 4;
#pragma unroll
            for (int r = 0; r < 4; ++r) {
                out[ob + rbase + r] = fmaxf(acc0[r] + bias, 0.f);           // rows 0..15
                out[ob + 16 + rbase + r] = fmaxf(acc1[r] + bias, 0.f);      // rows 16..31
                int row2 = 32 + rbase + r;
                if (row2 < 34) out[ob + row2] = fmaxf(acc2[r] + bias, 0.f); // rows 32..33
            }
        }
    }
}

extern "C" void kernel_launch(void* const* d_in, const int* in_sizes, int n_in,
                              void* d_out, int out_size, void* d_ws, size_t ws_size,
                              hipStream_t stream) {
    const float* x      = (const float*)d_in[0];
    const float* adj    = (const float*)d_in[1];
    const float* wq     = (const float*)d_in[2];
    const float* wk     = (const float*)d_in[3];
    const float* wv     = (const float*)d_in[4];
    const float* adj2   = (const float*)d_in[5];
    const float* conv_w = (const float*)d_in[6];
    const float* gamma  = (const float*)d_in[7];
    const float* beta   = (const float*)d_in[8];
    const float* mean   = (const float*)d_in[9];
    const float* var    = (const float*)d_in[10];
    char* ws   = (char*)d_ws;
    float* outp = (float*)d_out;

    const int B = in_sizes[0] / (DD * TT * NJ);

    prep_kernel<<<(PREP_ITEMS + 255) / 256, 256, 0, stream>>>(
        adj, wq, wk, wv, adj2, conv_w, gamma, beta, mean, var, ws);

    dim3 grid(TT / 2, B);
    gab_main<<<grid, 512, 0, stream>>>(x, ws, outp);
}

// Round 3
// 612.212 us; speedup vs baseline: 1.3918x; 1.3918x over previous
//
#include <hip/hip_runtime.h>
#include <hip/hip_bf16.h>
#include <math.h>

#define NJ 17
#define DD 128
#define TT 512
#define HH 16
#define CC 256
#define NEG_INF -9e15f

typedef __attribute__((ext_vector_type(8))) short short8;
typedef __attribute__((ext_vector_type(4))) float floatx4;
typedef _Float16 h8 __attribute__((ext_vector_type(8)));
typedef _Float16 h2 __attribute__((ext_vector_type(2)));

// ws BYTE offsets
#define WB_CONV 0            // bf16[65536]  conv_w*bnscale, fragment order (16 nt x 8 ks x 64 lane x 8)
#define WB_QKV  131072       // bf16[49152]  [Wq|Wk|Wv] cols, fragment order (24 nt x 4 ks x 64 lane x 8)
#define WB_MOFF 229376       // f32[16*17*17] additive mask offsets
#define WB_BIAS 247872       // f32[256]     fused BN bias
#define PREP_ITEMS (65536 + 49152 + 4624 + 256)

__global__ __launch_bounds__(256) void prep_kernel(
        const float* __restrict__ adj,
        const float* __restrict__ wq,
        const float* __restrict__ wk,
        const float* __restrict__ wv,
        const float* __restrict__ adj2,
        const float* __restrict__ conv_w,
        const float* __restrict__ gamma,
        const float* __restrict__ beta,
        const float* __restrict__ mean,
        const float* __restrict__ var,
        char* __restrict__ ws) {
    int g = blockIdx.x * 256 + threadIdx.x;
    if (g < 65536) {
        // conv fragments: idx = ((nt*8+ks)*64+lane)*8+j ; o = nt*16+(lane&15), c = ks*32+(lane>>4)*8+j
        int j = g & 7, lane = (g >> 3) & 63, kn = g >> 9;
        int ks = kn & 7, nt = kn >> 3;
        int o = nt * 16 + (lane & 15);
        int c = ks * 32 + ((lane >> 4) & 3) * 8 + j;
        float sg = gamma[o] * rsqrtf(var[o] + 1e-5f);
        ((__hip_bfloat16*)(ws + WB_CONV))[g] = __float2bfloat16(conv_w[o * CC + c] * sg);
        return;
    }
    g -= 65536;
    if (g < 49152) {
        // qkv fragments: idx = ((nt*4+ks)*64+lane)*8+j ; n = nt*16+(lane&15), k = ks*32+(lane>>4)*8+j
        int j = g & 7, lane = (g >> 3) & 63, kn = g >> 9;
        int ks = kn & 3, nt = kn >> 2;            // nt 0..23 over 384 cols: [q|k|v]
        int n = nt * 16 + (lane & 15);
        int k = ks * 32 + ((lane >> 4) & 3) * 8 + j;
        int mat = n >> 7;                          // 0=q 1=k 2=v
        int wcol = n & 127;
        int h = wcol >> 3, e = wcol & 7;
        const float* src = (mat == 0) ? wq : ((mat == 1) ? wk : wv);
        float v = src[(h * DD + k) * 8 + e];       // (H,D,hd) layout
        if (mat == 0) v *= 0.35355339059327373f;   // 1/sqrt(8) folded into Wq
        ((__hip_bfloat16*)(ws + WB_QKV))[g] = __float2bfloat16(v);
        return;
    }
    g -= 49152;
    if (g < HH * NJ * NJ) {
        int h = g / (NJ * NJ);
        int r = g - h * NJ * NJ;
        int n = r / NJ, m = r - n * NJ;
        float a1 = adj[n * NJ + m] + adj2[(h * NJ + n) * NJ + m];
        float a2 = adj[m * NJ + n] + adj2[(h * NJ + m) * NJ + n];
        ((float*)(ws + WB_MOFF))[g] = (0.5f * (a1 + a2) > 0.f) ? 0.f : NEG_INF;
        return;
    }
    g -= HH * NJ * NJ;
    if (g < CC) {
        float sg = gamma[g] * rsqrtf(var[g] + 1e-5f);
        ((float*)(ws + WB_BIAS))[g] = beta[g] - mean[g] * sg;
    }
}

// LDS layout:
//   cat: 34 rows x 264 bf16 (stride 528 B). cols 0..127 = xp, cols 128..255 = q (f16 bits,
//        phase 1/2) then attention output (bf16, phase 2/3).
//   kv : 2 x 34 x 128 f16 (k, v)
// MFMA M-tiles read "rows" 32..47; rows 34..47 are garbage (they alias kv) — harmless,
// since MFMA output rows are independent and rows >=34 are never stored.
#define CAT_STRIDE 264
#define LDS_CAT_BYTES (34 * CAT_STRIDE * 2)
#define LDS_TOTAL (LDS_CAT_BYTES + 2 * 34 * 128 * 2)

// 2nd arg: min-2-blocks/CU (CUDA semantics) or 2 waves/EU (guide semantics) —
// either way VGPR cap >=128, guaranteeing no spill (round-2 lesson: (512,6)
// produced a cap of 40 VGPRs -> ~1.2 GB scratch traffic).
__global__ __launch_bounds__(512, 2) void gab_main(
        const float* __restrict__ x,
        const char* __restrict__ ws,
        float* __restrict__ out) {
    // t-swizzle: XCD x gets a contiguous t-range so adjacent write runs merge in one L2
    const int tp = blockIdx.x;                       // 0..255 (token pairs)
    const int t0 = 2 * ((tp & 7) * 32 + (tp >> 3));
    const int b = blockIdx.y;
    const int tid = threadIdx.x;
    const int lane = tid & 63;
    const int wave = tid >> 6;                       // 0..7
    const int l15 = lane & 15;
    const int lq = lane >> 4;

    __shared__ __align__(16) char smem[LDS_TOTAL];
    __hip_bfloat16 (*cat)[CAT_STRIDE] = (__hip_bfloat16 (*)[CAT_STRIDE])smem;
    _Float16 (*kv)[34][128] = (_Float16 (*)[34][128])(smem + LDS_CAT_BYTES);

    // ---- Phase 0: stage xp -> cat[row][d] (row = lt*17+n). No zero-fill needed. ----
    const float* xb = x + (size_t)b * DD * TT * NJ + (size_t)t0 * NJ;
    for (int i = tid; i < DD * 17; i += 512) {
        int d = i / 17;
        int j = 2 * (i - d * 17);                   // 17 float2 cover j=0..33
        float2 f = *(const float2*)(xb + (size_t)d * (TT * NJ) + j);
        cat[j][d] = __float2bfloat16(f.x);
        cat[j + 1][d] = __float2bfloat16(f.y);
    }
    __syncthreads();

    // ---- Phase 1: QKV GEMM via MFMA. wave w owns Ntiles w*3..w*3+2 of 24 (cols: q|k|v) ----
    {
        const short8* bbase = (const short8*)(ws + WB_QKV);
        const int nt0 = wave * 3;
        for (int i = 0; i < 3; ++i) {
            const int nt = nt0 + i;
            floatx4 acc0 = {0.f, 0.f, 0.f, 0.f}, acc1 = acc0, acc2 = acc0;
            const short8* bp = bbase + (nt * 4) * 64 + lane;
#pragma unroll
            for (int ks = 0; ks < 4; ++ks) {
                short8 bf = bp[ks * 64];
                const int k0 = ks * 32 + lq * 8;
                short8 a0 = *(const short8*)&cat[l15][k0];
                short8 a1 = *(const short8*)&cat[16 + l15][k0];
                short8 a2 = *(const short8*)&cat[32 + l15][k0];   // rows 34..47: garbage, discarded
                acc0 = __builtin_amdgcn_mfma_f32_16x16x32_bf16(a0, bf, acc0, 0, 0, 0);
                acc1 = __builtin_amdgcn_mfma_f32_16x16x32_bf16(a1, bf, acc1, 0, 0, 0);
                acc2 = __builtin_amdgcn_mfma_f32_16x16x32_bf16(a2, bf, acc2, 0, 0, 0);
            }
            const int col = nt * 16 + l15;
            const int mat = col >> 7;                // wave-uniform (16-col tiles never straddle 128)
            const int mc = col & 127;
            const int rbase = lq * 4;
            if (mat == 0) {
                // q lives as f16 bits in cat's attn half; consumed (and overwritten) in phase 2
                _Float16* qd = (_Float16*)smem + 128 + mc;
#pragma unroll
                for (int r = 0; r < 4; ++r) {
                    qd[(rbase + r) * CAT_STRIDE] = (_Float16)acc0[r];
                    qd[(16 + rbase + r) * CAT_STRIDE] = (_Float16)acc1[r];
                    int row2 = 32 + rbase + r;
                    if (row2 < 34) qd[row2 * CAT_STRIDE] = (_Float16)acc2[r];
                }
            } else {
                _Float16* kd = &kv[mat - 1][0][mc];
#pragma unroll
                for (int r = 0; r < 4; ++r) {
                    kd[(rbase + r) * 128] = (_Float16)acc0[r];
                    kd[(16 + rbase + r) * 128] = (_Float16)acc1[r];
                    int row2 = 32 + rbase + r;
                    if (row2 < 34) kd[row2 * 128] = (_Float16)acc2[r];
                }
            }
        }
    }
    __syncthreads();

    // ---- Phase 2: attention per (t,h,n), single fused pass.
    //      softmax WITHOUT max-subtraction: scores are O(+-6) (scale folded into Wq),
    //      masked entries get -9e15 -> expf -> 0 exactly; shift-invariance makes this
    //      mathematically identical to the reference. Deletes s[17] (reg pressure) and
    //      two extra passes (VALU). ----
    {
        const float* moff = (const float*)(ws + WB_MOFF);
        for (int it = tid; it < 2 * HH * NJ; it += 512) {
            const int t = it / (HH * NJ);
            const int r2 = it - t * (HH * NJ);
            const int h = r2 / NJ;
            const int n = r2 - h * NJ;
            const int row = t * NJ + n;
            const float* mo = moff + (h * NJ + n) * NJ;
            const h8 qv = *(const h8*)((const _Float16*)smem + row * CAT_STRIDE + 128 + h * 8);
            const h2* q2 = (const h2*)&qv;
            const _Float16* kbase = &kv[0][t * NJ][h * 8];
            const _Float16* vbase = &kv[1][t * NJ][h * 8];
            float sum = 0.f;
            float ov[8];
#pragma unroll
            for (int e = 0; e < 8; ++e) ov[e] = 0.f;
#pragma unroll
            for (int m = 0; m < NJ; ++m) {
                const h8 kvec = *(const h8*)(kbase + m * 128);
                float a = mo[m];
#if __has_builtin(__builtin_amdgcn_fdot2)
                const h2* k2 = (const h2*)&kvec;
                a = __builtin_amdgcn_fdot2(q2[0], k2[0], a, false);
                a = __builtin_amdgcn_fdot2(q2[1], k2[1], a, false);
                a = __builtin_amdgcn_fdot2(q2[2], k2[2], a, false);
                a = __builtin_amdgcn_fdot2(q2[3], k2[3], a, false);
#else
#pragma unroll
                for (int e = 0; e < 8; ++e) a += (float)qv[e] * (float)kvec[e];
#endif
                const float p = __expf(a);
                sum += p;
                const h8 vvec = *(const h8*)(vbase + m * 128);
#pragma unroll
                for (int e = 0; e < 8; ++e) ov[e] += p * (float)vvec[e];
            }
            const float inv = 1.0f / sum;
            __hip_bfloat16 tmp[8];
#pragma unroll
            for (int e = 0; e < 8; ++e) tmp[e] = __float2bfloat16(ov[e] * inv);
            *(short8*)((__hip_bfloat16*)smem + row * CAT_STRIDE + 128 + h * 8) = *(short8*)tmp;
        }
    }
    __syncthreads();

    // ---- Phase 3: conv1x1 GEMM via MFMA + BN bias + ReLU. wave w owns Ntiles w*2..w*2+1 ----
    {
        const short8* cbase = (const short8*)(ws + WB_CONV);
        const float* biasp = (const float*)(ws + WB_BIAS);
        const int nt0 = wave * 2;
        for (int i = 0; i < 2; ++i) {
            const int nt = nt0 + i;
            floatx4 acc0 = {0.f, 0.f, 0.f, 0.f}, acc1 = acc0, acc2 = acc0;
            const short8* bp = cbase + (nt * 8) * 64 + lane;
#pragma unroll
            for (int ks = 0; ks < 8; ++ks) {
                short8 bf = bp[ks * 64];
                const int k0 = ks * 32 + lq * 8;
                short8 a0 = *(const short8*)&cat[l15][k0];
                short8 a1 = *(const short8*)&cat[16 + l15][k0];
                short8 a2 = *(const short8*)&cat[32 + l15][k0];   // rows 34..47: garbage, discarded
                acc0 = __builtin_amdgcn_mfma_f32_16x16x32_bf16(a0, bf, acc0, 0, 0, 0);
                acc1 = __builtin_amdgcn_mfma_f32_16x16x32_bf16(a1, bf, acc1, 0, 0, 0);
                acc2 = __builtin_amdgcn_mfma_f32_16x16x32_bf16(a2, bf, acc2, 0, 0, 0);
            }
            const int o = nt * 16 + l15;
            const float bias = biasp[o];
            const size_t ob = ((size_t)b * CC + o) * (TT * NJ) + (size_t)t0 * NJ;
            const int rbase = lq * 4;
#pragma unroll
            for (int r = 0; r < 4; ++r) {
                out[ob + rbase + r] = fmaxf(acc0[r] + bias, 0.f);           // rows 0..15
                out[ob + 16 + rbase + r] = fmaxf(acc1[r] + bias, 0.f);      // rows 16..31
                int row2 = 32 + rbase + r;
                if (row2 < 34) out[ob + row2] = fmaxf(acc2[r] + bias, 0.f); // rows 32..33
            }
        }
    }
}

extern "C" void kernel_launch(void* const* d_in, const int* in_sizes, int n_in,
                              void* d_out, int out_size, void* d_ws, size_t ws_size,
                              hipStream_t stream) {
    const float* x      = (const float*)d_in[0];
    const float* adj    = (const float*)d_in[1];
    const float* wq     = (const float*)d_in[2];
    const float* wk     = (const float*)d_in[3];
    const float* wv     = (const float*)d_in[4];
    const float* adj2   = (const float*)d_in[5];
    const float* conv_w = (const float*)d_in[6];
    const float* gamma  = (const float*)d_in[7];
    const float* beta   = (const float*)d_in[8];
    const float* mean   = (const float*)d_in[9];
    const float* var    = (const float*)d_in[10];
    char* ws   = (char*)d_ws;
    float* outp = (float*)d_out;

    const int B = in_sizes[0] / (DD * TT * NJ);

    prep_kernel<<<(PREP_ITEMS + 255) / 256, 256, 0, stream>>>(
        adj, wq, wk, wv, adj2, conv_w, gamma, beta, mean, var, ws);

    dim3 grid(TT / 2, B);
    gab_main<<<grid, 512, 0, stream>>>(x, ws, outp);
}

// Round 4
// 579.299 us; speedup vs baseline: 1.4708x; 1.0568x over previous
//
#include <hip/hip_runtime.h>
#include <hip/hip_bf16.h>
#include <math.h>

#define NJ 17
#define DD 128
#define TT 512
#define HH 16
#define CC 256
#define NEG_INF -9e15f

typedef __attribute__((ext_vector_type(8))) short short8;
typedef __attribute__((ext_vector_type(4))) float floatx4;
typedef __attribute__((ext_vector_type(4), aligned(4))) float float4u;  // 4B-aligned vector load
typedef __attribute__((ext_vector_type(2), aligned(4))) float float2u;
typedef _Float16 h8 __attribute__((ext_vector_type(8)));
typedef _Float16 h2 __attribute__((ext_vector_type(2)));

// ws BYTE offsets
#define WB_CONV 0            // bf16[65536]  conv_w*bnscale, fragment order (16 nt x 8 ks x 64 lane x 8)
#define WB_QKV  131072       // bf16[49152]  [Wq|Wk|Wv] cols, fragment order (24 nt x 4 ks x 64 lane x 8)
#define WB_MOFF 229376       // u32[16*17]   adjacency bitmask per (h,n): bit m = edge allowed
#define WB_BIAS 247872       // f32[256]     fused BN bias
#define PREP_ITEMS (65536 + 49152 + 272 + 256)

__global__ __launch_bounds__(256) void prep_kernel(
        const float* __restrict__ adj,
        const float* __restrict__ wq,
        const float* __restrict__ wk,
        const float* __restrict__ wv,
        const float* __restrict__ adj2,
        const float* __restrict__ conv_w,
        const float* __restrict__ gamma,
        const float* __restrict__ beta,
        const float* __restrict__ mean,
        const float* __restrict__ var,
        char* __restrict__ ws) {
    int g = blockIdx.x * 256 + threadIdx.x;
    if (g < 65536) {
        // conv fragments: idx = ((nt*8+ks)*64+lane)*8+j ; o = nt*16+(lane&15), c = ks*32+(lane>>4)*8+j
        int j = g & 7, lane = (g >> 3) & 63, kn = g >> 9;
        int ks = kn & 7, nt = kn >> 3;
        int o = nt * 16 + (lane & 15);
        int c = ks * 32 + ((lane >> 4) & 3) * 8 + j;
        float sg = gamma[o] * rsqrtf(var[o] + 1e-5f);
        ((__hip_bfloat16*)(ws + WB_CONV))[g] = __float2bfloat16(conv_w[o * CC + c] * sg);
        return;
    }
    g -= 65536;
    if (g < 49152) {
        // qkv fragments: idx = ((nt*4+ks)*64+lane)*8+j ; n = nt*16+(lane&15), k = ks*32+(lane>>4)*8+j
        int j = g & 7, lane = (g >> 3) & 63, kn = g >> 9;
        int ks = kn & 3, nt = kn >> 2;            // nt 0..23 over 384 cols: [q|k|v]
        int n = nt * 16 + (lane & 15);
        int k = ks * 32 + ((lane >> 4) & 3) * 8 + j;
        int mat = n >> 7;                          // 0=q 1=k 2=v
        int wcol = n & 127;
        int h = wcol >> 3, e = wcol & 7;
        const float* src = (mat == 0) ? wq : ((mat == 1) ? wk : wv);
        float v = src[(h * DD + k) * 8 + e];       // (H,D,hd) layout
        // fold 1/sqrt(8) AND log2(e) into Wq so phase 2 uses raw v_exp (2^x)
        if (mat == 0) v *= 0.35355339059327373f * 1.4426950408889634f;
        ((__hip_bfloat16*)(ws + WB_QKV))[g] = __float2bfloat16(v);
        return;
    }
    g -= 49152;
    if (g < HH * NJ) {
        int h = g / NJ, n = g - h * NJ;
        unsigned bits = 0;
        for (int m = 0; m < NJ; ++m) {
            float a1 = adj[n * NJ + m] + adj2[(h * NJ + n) * NJ + m];
            float a2 = adj[m * NJ + n] + adj2[(h * NJ + m) * NJ + n];
            if (0.5f * (a1 + a2) > 0.f) bits |= (1u << m);
        }
        ((unsigned*)(ws + WB_MOFF))[g] = bits;
        return;
    }
    g -= HH * NJ;
    if (g < CC) {
        float sg = gamma[g] * rsqrtf(var[g] + 1e-5f);
        ((float*)(ws + WB_BIAS))[g] = beta[g] - mean[g] * sg;
    }
}

// LDS layout:
//   cat: 34 rows x 264 bf16 (stride 528 B). cols 0..127 = xp, cols 128..255 = q (f16 bits,
//        phase 1/2) then attention output (bf16, phase 2/3).
//   kv : 2 x 34 x 136 f16 (k, v) — stride 136 (272 B) so fragment writes are 2-way not 4-way
// MFMA M-tiles read "rows" 32..47; rows 34..47 are garbage (alias kv) — harmless: MFMA
// output rows are independent and rows >=34 are never stored.
#define CAT_STRIDE 264
#define KV_STRIDE 136
#define LDS_CAT_BYTES (34 * CAT_STRIDE * 2)
#define LDS_TOTAL (LDS_CAT_BYTES + 2 * 34 * KV_STRIDE * 2)

// (512,4): CUDA block semantics (proven round 2: arg=6 gave cap 40 = 512/12) ->
// 4 blocks/CU = 32 waves = 8 waves/EU -> VGPR cap 64, exactly matching the LDS limit.
__global__ __launch_bounds__(512, 4) void gab_main(
        const float* __restrict__ x,
        const char* __restrict__ ws,
        float* __restrict__ out) {
    // t-swizzle: XCD x gets a contiguous t-range so adjacent write runs merge in one L2
    const int tp = blockIdx.x;                       // 0..255 (token pairs)
    const int t0 = 2 * ((tp & 7) * 32 + (tp >> 3));
    const int b = blockIdx.y;
    const int tid = threadIdx.x;
    const int lane = tid & 63;
    const int wave = tid >> 6;                       // 0..7
    const int l15 = lane & 15;
    const int lq = lane >> 4;

    __shared__ __align__(16) char smem[LDS_TOTAL];
    __hip_bfloat16 (*cat)[CAT_STRIDE] = (__hip_bfloat16 (*)[CAT_STRIDE])smem;
    _Float16 (*kv)[34][KV_STRIDE] = (_Float16 (*)[34][KV_STRIDE])(smem + LDS_CAT_BYTES);

    // ---- Phase 0: stage xp -> cat[row][d] (row = lt*17+n), float4 global loads ----
    const float* xb = x + (size_t)b * DD * TT * NJ + (size_t)t0 * NJ;
    for (int i = tid; i < DD * 9; i += 512) {
        int d = i / 9;
        int c = i - d * 9;
        const float* src = xb + (size_t)d * (TT * NJ);
        if (c < 8) {
            float4u f = *(const float4u*)(src + 4 * c);
            int j = 4 * c;
            cat[j][d]     = __float2bfloat16(f.x);
            cat[j + 1][d] = __float2bfloat16(f.y);
            cat[j + 2][d] = __float2bfloat16(f.z);
            cat[j + 3][d] = __float2bfloat16(f.w);
        } else {
            float2u f = *(const float2u*)(src + 32);
            cat[32][d] = __float2bfloat16(f.x);
            cat[33][d] = __float2bfloat16(f.y);
        }
    }
    __syncthreads();

    // ---- Phase 1: QKV GEMM. ks-outer so A-fragments load once per ks (LDS-pipe cut).
    //      wave w owns Ntiles w*3..w*3+2 of 24 (cols: q|k|v), processed as pair + single. ----
    {
        const short8* bbase = (const short8*)(ws + WB_QKV);
        const int nt0 = wave * 3;

        auto store_qkv = [&](int nt, const floatx4& v0, const floatx4& v1, const floatx4& v2) {
            const int col = nt * 16 + l15;
            const int mat = col >> 7;                // wave-uniform (tiles never straddle 128)
            const int mc = col & 127;
            const int rbase = lq * 4;
            if (mat == 0) {
                _Float16* qd = (_Float16*)smem + 128 + mc;   // q into cat's attn half (f16 bits)
#pragma unroll
                for (int r = 0; r < 4; ++r) {
                    qd[(rbase + r) * CAT_STRIDE] = (_Float16)v0[r];
                    qd[(16 + rbase + r) * CAT_STRIDE] = (_Float16)v1[r];
                    int row2 = 32 + rbase + r;
                    if (row2 < 34) qd[row2 * CAT_STRIDE] = (_Float16)v2[r];
                }
            } else {
                _Float16* kd = &kv[mat - 1][0][mc];
#pragma unroll
                for (int r = 0; r < 4; ++r) {
                    kd[(rbase + r) * KV_STRIDE] = (_Float16)v0[r];
                    kd[(16 + rbase + r) * KV_STRIDE] = (_Float16)v1[r];
                    int row2 = 32 + rbase + r;
                    if (row2 < 34) kd[row2 * KV_STRIDE] = (_Float16)v2[r];
                }
            }
        };

        // pair {nt0, nt0+1}
        {
            floatx4 acc[2][3];
#pragma unroll
            for (int u = 0; u < 2; ++u)
#pragma unroll
                for (int m = 0; m < 3; ++m) acc[u][m] = (floatx4){0.f, 0.f, 0.f, 0.f};
#pragma unroll
            for (int ks = 0; ks < 4; ++ks) {
                const int k0 = ks * 32 + lq * 8;
                short8 a0 = *(const short8*)&cat[l15][k0];
                short8 a1 = *(const short8*)&cat[16 + l15][k0];
                short8 a2 = *(const short8*)&cat[32 + l15][k0];   // rows>=34: garbage, discarded
#pragma unroll
                for (int u = 0; u < 2; ++u) {
                    short8 bf = bbase[((nt0 + u) * 4 + ks) * 64 + lane];
                    acc[u][0] = __builtin_amdgcn_mfma_f32_16x16x32_bf16(a0, bf, acc[u][0], 0, 0, 0);
                    acc[u][1] = __builtin_amdgcn_mfma_f32_16x16x32_bf16(a1, bf, acc[u][1], 0, 0, 0);
                    acc[u][2] = __builtin_amdgcn_mfma_f32_16x16x32_bf16(a2, bf, acc[u][2], 0, 0, 0);
                }
            }
            store_qkv(nt0, acc[0][0], acc[0][1], acc[0][2]);
            store_qkv(nt0 + 1, acc[1][0], acc[1][1], acc[1][2]);
        }
        // singleton {nt0+2}
        {
            floatx4 acc0 = {0.f, 0.f, 0.f, 0.f}, acc1 = acc0, acc2 = acc0;
#pragma unroll
            for (int ks = 0; ks < 4; ++ks) {
                const int k0 = ks * 32 + lq * 8;
                short8 a0 = *(const short8*)&cat[l15][k0];
                short8 a1 = *(const short8*)&cat[16 + l15][k0];
                short8 a2 = *(const short8*)&cat[32 + l15][k0];
                short8 bf = bbase[((nt0 + 2) * 4 + ks) * 64 + lane];
                acc0 = __builtin_amdgcn_mfma_f32_16x16x32_bf16(a0, bf, acc0, 0, 0, 0);
                acc1 = __builtin_amdgcn_mfma_f32_16x16x32_bf16(a1, bf, acc1, 0, 0, 0);
                acc2 = __builtin_amdgcn_mfma_f32_16x16x32_bf16(a2, bf, acc2, 0, 0, 0);
            }
            store_qkv(nt0 + 2, acc0, acc1, acc2);
        }
    }
    __syncthreads();

    // ---- Phase 2: attention per (t,h,n), single fused pass, no max-subtraction
    //      (scores O(+-10) in log2 space; masked -> 2^(-9e15) = 0 exactly; shift-invariant).
    //      Mask from L1-resident bitmask table (1 u32 load vs 17 f32 loads). ----
    {
        const unsigned* mbits = (const unsigned*)(ws + WB_MOFF);
        for (int it = tid; it < 2 * HH * NJ; it += 512) {
            const int t = it / (HH * NJ);
            const int r2 = it - t * (HH * NJ);
            const int h = r2 / NJ;
            const int n = r2 - h * NJ;
            const int row = t * NJ + n;
            const unsigned bits = mbits[h * NJ + n];
            const h8 qv = *(const h8*)((const _Float16*)smem + row * CAT_STRIDE + 128 + h * 8);
            const h2* q2 = (const h2*)&qv;
            const _Float16* kbase = &kv[0][t * NJ][h * 8];
            const _Float16* vbase = &kv[1][t * NJ][h * 8];
            float sum = 0.f;
            float ov[8];
#pragma unroll
            for (int e = 0; e < 8; ++e) ov[e] = 0.f;
#pragma unroll
            for (int m = 0; m < NJ; ++m) {
                const h8 kvec = *(const h8*)(kbase + m * KV_STRIDE);
                float a = 0.f;
#if __has_builtin(__builtin_amdgcn_fdot2)
                const h2* k2 = (const h2*)&kvec;
                a = __builtin_amdgcn_fdot2(q2[0], k2[0], a, false);
                a = __builtin_amdgcn_fdot2(q2[1], k2[1], a, false);
                a = __builtin_amdgcn_fdot2(q2[2], k2[2], a, false);
                a = __builtin_amdgcn_fdot2(q2[3], k2[3], a, false);
#else
#pragma unroll
                for (int e = 0; e < 8; ++e) a += (float)qv[e] * (float)kvec[e];
#endif
                a = ((bits >> m) & 1u) ? a : NEG_INF;
#if __has_builtin(__builtin_amdgcn_exp2f)
                const float p = __builtin_amdgcn_exp2f(a);
#else
                const float p = __expf(a * 0.6931471805599453f);
#endif
                sum += p;
                const h8 vvec = *(const h8*)(vbase + m * KV_STRIDE);
#pragma unroll
                for (int e = 0; e < 8; ++e) ov[e] += p * (float)vvec[e];
            }
            const float inv = 1.0f / sum;
            __hip_bfloat16 tmp[8];
#pragma unroll
            for (int e = 0; e < 8; ++e) tmp[e] = __float2bfloat16(ov[e] * inv);
            *(short8*)((__hip_bfloat16*)smem + row * CAT_STRIDE + 128 + h * 8) = *(short8*)tmp;
        }
    }
    __syncthreads();

    // ---- Phase 3: conv1x1 GEMM + BN bias + ReLU. ks-outer, both nt together. ----
    {
        const short8* cbase = (const short8*)(ws + WB_CONV);
        const float* biasp = (const float*)(ws + WB_BIAS);
        const int nt0 = wave * 2;
        floatx4 acc[2][3];
#pragma unroll
        for (int u = 0; u < 2; ++u)
#pragma unroll
            for (int m = 0; m < 3; ++m) acc[u][m] = (floatx4){0.f, 0.f, 0.f, 0.f};
#pragma unroll
        for (int ks = 0; ks < 8; ++ks) {
            const int k0 = ks * 32 + lq * 8;
            short8 a0 = *(const short8*)&cat[l15][k0];
            short8 a1 = *(const short8*)&cat[16 + l15][k0];
            short8 a2 = *(const short8*)&cat[32 + l15][k0];   // rows>=34: garbage, discarded
#pragma unroll
            for (int u = 0; u < 2; ++u) {
                short8 bf = cbase[((nt0 + u) * 8 + ks) * 64 + lane];
                acc[u][0] = __builtin_amdgcn_mfma_f32_16x16x32_bf16(a0, bf, acc[u][0], 0, 0, 0);
                acc[u][1] = __builtin_amdgcn_mfma_f32_16x16x32_bf16(a1, bf, acc[u][1], 0, 0, 0);
                acc[u][2] = __builtin_amdgcn_mfma_f32_16x16x32_bf16(a2, bf, acc[u][2], 0, 0, 0);
            }
        }
#pragma unroll
        for (int u = 0; u < 2; ++u) {
            const int o = (nt0 + u) * 16 + l15;
            const float bias = biasp[o];
            const size_t ob = ((size_t)b * CC + o) * (TT * NJ) + (size_t)t0 * NJ;
            const int rbase = lq * 4;
#pragma unroll
            for (int r = 0; r < 4; ++r) {
                out[ob + rbase + r] = fmaxf(acc[u][0][r] + bias, 0.f);           // rows 0..15
                out[ob + 16 + rbase + r] = fmaxf(acc[u][1][r] + bias, 0.f);      // rows 16..31
                int row2 = 32 + rbase + r;
                if (row2 < 34) out[ob + row2] = fmaxf(acc[u][2][r] + bias, 0.f); // rows 32..33
            }
        }
    }
}

extern "C" void kernel_launch(void* const* d_in, const int* in_sizes, int n_in,
                              void* d_out, int out_size, void* d_ws, size_t ws_size,
                              hipStream_t stream) {
    const float* x      = (const float*)d_in[0];
    const float* adj    = (const float*)d_in[1];
    const float* wq     = (const float*)d_in[2];
    const float* wk     = (const float*)d_in[3];
    const float* wv     = (const float*)d_in[4];
    const float* adj2   = (const float*)d_in[5];
    const float* conv_w = (const float*)d_in[6];
    const float* gamma  = (const float*)d_in[7];
    const float* beta   = (const float*)d_in[8];
    const float* mean   = (const float*)d_in[9];
    const float* var    = (const float*)d_in[10];
    char* ws   = (char*)d_ws;
    float* outp = (float*)d_out;

    const int B = in_sizes[0] / (DD * TT * NJ);

    prep_kernel<<<(PREP_ITEMS + 255) / 256, 256, 0, stream>>>(
        adj, wq, wk, wv, adj2, conv_w, gamma, beta, mean, var, ws);

    dim3 grid(TT / 2, B);
    gab_main<<<grid, 512, 0, stream>>>(x, ws, outp);
}